// Round 1
// 653.673 us; speedup vs baseline: 1.5786x; 1.5786x over previous
//
#include <hip/hip_runtime.h>
#include <cstdint>

#define NIN     2000
#define NRES    50
#define NOUT    500
#define TSTEPS  512
#define NBATCH  64
#define BT      32768   // NBATCH * TSTEPS
#define KPAD    2048    // W k-dim padded (zeros past 2000)
#define NPAD    64      // W n-dim padded (zeros past 50)
#define KSTEPS  63      // 63*32 = 2016 >= 2000; B zero-padded kills k in [2000,2016)
#define KCLAMP  1996    // last valid float4 base within a 2000-float U row

typedef __bf16 bf16x8 __attribute__((ext_vector_type(8)));
typedef float  f32x4  __attribute__((ext_vector_type(4)));

// tanh(x) = 1 - 2/(e^{2x}+1). Overflow-safe without clamping:
// x >> 0: e=inf -> rcp(inf)=0 -> 1 ; x << 0: e=0 -> 1-2 = -1. No NaN path.
__device__ __forceinline__ float fast_tanh(float x) {
  float e = __expf(2.0f * x);
  return fmaf(-2.0f, __builtin_amdgcn_rcpf(e + 1.0f), 1.0f);
}

// x = hi + lo with hi = RN-bf16(x) (lo then exact in fp32, Dekker), lo truncated
// to bf16 (error ~2^-16 relative to x). Inputs here are tanh outputs / small
// uniform weights: no inf/NaN, no rounding overflow.
__device__ __forceinline__ void bf16_split(float x, unsigned short& h, unsigned short& l) {
  unsigned u  = __float_as_uint(x);
  unsigned hb = (u + 0x7FFFu + ((u >> 16) & 1u)) & 0xFFFF0000u;
  h = (unsigned short)(hb >> 16);
  float lo = x - __uint_as_float(hb);
  l = (unsigned short)(__float_as_uint(lo) >> 16);
}

union ABfrag { unsigned short u16[8]; bf16x8 v; };

// ---- kernel 0: split W_in into zero-padded bf16 hi/lo planes [NPAD][KPAD] ----
__global__ __launch_bounds__(256) void prep_kernel(const float* __restrict__ Win,
                                                   unsigned short* __restrict__ Whi,
                                                   unsigned short* __restrict__ Wlo) {
  int idx = blockIdx.x * 256 + threadIdx.x;   // 0 .. NPAD*KPAD-1 (131072)
  int n = idx >> 11;                          // KPAD = 2^11
  int k = idx & (KPAD - 1);
  float x = (n < NRES && k < NIN) ? Win[n * NIN + k] : 0.0f;
  unsigned short h, l;
  bf16_split(x, h, l);
  Whi[idx] = h;
  Wlo[idx] = l;
}

// ---- kernel 1: P[bt][r] = sum_k tanh(U[bt][k]) * W_in[r][k] via 3-pass bf16 MFMA
// One wave owns a 16-row x 64-col tile (cols 50..63 hit zero-padded B -> acc 0,
// never stored). K loop: per lane 8 contiguous fp32 U elems (reg double-buffered),
// tanh + hi/lo split in-register; B frags are 16B loads from the L2-resident
// Wsplit planes. acc += Ah*Bh + Al*Bh + Ah*Bl (ll term dropped, ~2^-18).
// K-tail: per-lane source address clamped to KCLAMP; duplicated data lands in
// logical k>=2000 slots where B is exactly zero.
__global__ __launch_bounds__(256) void proj_mfma(const float* __restrict__ U,
                                                 const unsigned short* __restrict__ Whi,
                                                 const unsigned short* __restrict__ Wlo,
                                                 float* __restrict__ P) {
  const int wave = threadIdx.x >> 6;
  const int lane = threadIdx.x & 63;
  const int mrow = lane & 15;        // A row / C col within tile
  const int g    = lane >> 4;        // k-group (and C row group)
  const int g8   = g * 8;
  const int row0 = (blockIdx.x * 4 + wave) * 16;

  const float* __restrict__ u = U + (size_t)(row0 + mrow) * NIN;

  const unsigned short* bhp[4];
  const unsigned short* blp[4];
#pragma unroll
  for (int f = 0; f < 4; ++f) {
    const int n = f * 16 + mrow;     // B col
    bhp[f] = Whi + n * KPAD + g8;
    blp[f] = Wlo + n * KPAD + g8;
  }

  f32x4 acc[4] = {};

  float4 ca = *(const float4*)(u + min(g8, KCLAMP));
  float4 cb = *(const float4*)(u + min(g8 + 4, KCLAMP));

  for (int s = 0; s < KSTEPS; ++s) {
    const int k0 = s * 32;
    const int kn = k0 + 32;
    // next-step U prefetch (clamped: last iteration's fetch is a safe dup)
    float4 na = *(const float4*)(u + min(kn + g8, KCLAMP));
    float4 nb = *(const float4*)(u + min(kn + g8 + 4, KCLAMP));

    bf16x8 bh[4], bl[4];
#pragma unroll
    for (int f = 0; f < 4; ++f) {
      bh[f] = *(const bf16x8*)(bhp[f] + k0);
      bl[f] = *(const bf16x8*)(blp[f] + k0);
    }

    float t[8];
    t[0] = fast_tanh(ca.x); t[1] = fast_tanh(ca.y);
    t[2] = fast_tanh(ca.z); t[3] = fast_tanh(ca.w);
    t[4] = fast_tanh(cb.x); t[5] = fast_tanh(cb.y);
    t[6] = fast_tanh(cb.z); t[7] = fast_tanh(cb.w);

    ABfrag ah, al;
#pragma unroll
    for (int j = 0; j < 8; ++j) bf16_split(t[j], ah.u16[j], al.u16[j]);

#pragma unroll
    for (int f = 0; f < 4; ++f)
      acc[f] = __builtin_amdgcn_mfma_f32_16x16x32_bf16(ah.v, bh[f], acc[f], 0, 0, 0);
#pragma unroll
    for (int f = 0; f < 4; ++f)
      acc[f] = __builtin_amdgcn_mfma_f32_16x16x32_bf16(al.v, bh[f], acc[f], 0, 0, 0);
#pragma unroll
    for (int f = 0; f < 4; ++f)
      acc[f] = __builtin_amdgcn_mfma_f32_16x16x32_bf16(ah.v, bl[f], acc[f], 0, 0, 0);

    ca = na; cb = nb;
  }

  // C/D layout (verified m89): col = lane&15, row = (lane>>4)*4 + i
#pragma unroll
  for (int f = 0; f < 4; ++f) {
    const int col = f * 16 + mrow;
    if (col < NRES) {
#pragma unroll
      for (int i = 0; i < 4; ++i) {
        const int r = row0 + g * 4 + i;
        P[(size_t)r * NRES + col] = acc[f][i];
      }
    }
  }
}

// ---- kernel 2: sequential recurrence (one wave per batch row) + fused readout ----
// UNCHANGED from verified baseline (isolating the proj rewrite this round).
__global__ __launch_bounds__(64) void recur_kernel(const float* __restrict__ P,
                                                   const float* __restrict__ W_res,
                                                   const float* __restrict__ W_out,
                                                   const float* __restrict__ bias,
                                                   float* __restrict__ out) {
  const int b    = blockIdx.x;
  const int lane = threadIdx.x;
  const int r    = (lane < NRES) ? lane : 0;   // lanes 50-63 mirror lane 0 (never read back)

  float w[NRES];
#pragma unroll
  for (int j = 0; j < NRES; ++j) w[j] = W_res[r * NRES + j];

  const float* Pb = P + (size_t)b * TSTEPS * NRES;
  float state = 0.0f;

  float pring[8];
#pragma unroll
  for (int i = 0; i < 8; ++i) pring[i] = Pb[i * NRES + r];

#pragma unroll 8
  for (int t = 0; t < TSTEPS; ++t) {
    float pcur = pring[t & 7];
    if (t + 8 < TSTEPS) pring[t & 7] = Pb[(t + 8) * NRES + r];

    // 4-way split accumulator to shorten the serial FMA chain
    float a0 = pcur, a1 = 0.0f, a2 = 0.0f, a3 = 0.0f;
#pragma unroll
    for (int j = 0; j < 48; j += 4) {
      float s0 = __uint_as_float(__builtin_amdgcn_readlane(__float_as_uint(state), j + 0));
      float s1 = __uint_as_float(__builtin_amdgcn_readlane(__float_as_uint(state), j + 1));
      float s2 = __uint_as_float(__builtin_amdgcn_readlane(__float_as_uint(state), j + 2));
      float s3 = __uint_as_float(__builtin_amdgcn_readlane(__float_as_uint(state), j + 3));
      a0 = fmaf(s0, w[j + 0], a0);
      a1 = fmaf(s1, w[j + 1], a1);
      a2 = fmaf(s2, w[j + 2], a2);
      a3 = fmaf(s3, w[j + 3], a3);
    }
    {
      float s0 = __uint_as_float(__builtin_amdgcn_readlane(__float_as_uint(state), 48));
      float s1 = __uint_as_float(__builtin_amdgcn_readlane(__float_as_uint(state), 49));
      a0 = fmaf(s0, w[48], a0);
      a1 = fmaf(s1, w[49], a1);
    }
    state = fast_tanh((a0 + a1) + (a2 + a3));
  }

  // readout: out[b][o] = tanh(sum_j state[j] * W_out[j][o] + bias[o])
#pragma unroll
  for (int kk = 0; kk < 8; ++kk) {
    int o = kk * 64 + lane;
    if (o < NOUT) {
      float a0 = bias[o];
      float a1 = 0.0f;
#pragma unroll
      for (int j = 0; j < NRES; j += 2) {
        float s0 = __uint_as_float(__builtin_amdgcn_readlane(__float_as_uint(state), j));
        float s1 = __uint_as_float(__builtin_amdgcn_readlane(__float_as_uint(state), j + 1));
        a0 = fmaf(s0, W_out[j * NOUT + o], a0);
        a1 = fmaf(s1, W_out[(j + 1) * NOUT + o], a1);
      }
      out[b * NOUT + o] = fast_tanh(a0 + a1);
    }
  }
}

extern "C" void kernel_launch(void* const* d_in, const int* in_sizes, int n_in,
                              void* d_out, int out_size, void* d_ws, size_t ws_size,
                              hipStream_t stream) {
  const float* inputs = (const float*)d_in[0];
  const float* W_in   = (const float*)d_in[1];
  const float* W_res  = (const float*)d_in[2];
  const float* W_out  = (const float*)d_in[3];
  const float* bias   = (const float*)d_in[4];
  float* out = (float*)d_out;

  // ws layout: P f32 [32768][50] at 0 (6,553,600 B, fully overwritten by proj_mfma),
  // then Whi/Wlo bf16 [64][2048] (262,144 B each). Total ~7.08 MB.
  float* P = (float*)d_ws;
  unsigned short* Whi = (unsigned short*)((char*)d_ws + (size_t)BT * NRES * 4);
  unsigned short* Wlo = Whi + NPAD * KPAD;

  prep_kernel<<<(NPAD * KPAD) / 256, 256, 0, stream>>>(W_in, Whi, Wlo);
  proj_mfma<<<BT / 64, 256, 0, stream>>>(inputs, Whi, Wlo, P);
  recur_kernel<<<NBATCH, 64, 0, stream>>>(P, W_res, W_out, bias, out);
}